// Round 9
// baseline (7956.504 us; speedup 1.0000x reference)
//
#include <hip/hip_runtime.h>
#include <hip/hip_bf16.h>
#include <math.h>

#define T_STEPS 512
#define BATCH   64
#define HID     1024
#define G3      3072
#define BH      (BATCH * HID)

typedef __attribute__((ext_vector_type(8))) short          bf16x8;
typedef __attribute__((ext_vector_type(8))) unsigned short u16x8;
typedef __attribute__((ext_vector_type(4))) float          f32x4;
typedef unsigned long long u64;

__device__ inline unsigned short f2bf(float f) {
    __hip_bfloat16 h = __float2bfloat16(f);
    return *reinterpret_cast<unsigned short*>(&h);
}

// agent-scope (cross-XCD coherent) 16B load of bf16x8, bypassing stale L1/L2
__device__ inline bf16x8 load_h8(const unsigned short* p) {
    u64 lo = __hip_atomic_load((const u64*)p,       __ATOMIC_RELAXED, __HIP_MEMORY_SCOPE_AGENT);
    u64 hi = __hip_atomic_load((const u64*)(p + 4), __ATOMIC_RELAXED, __HIP_MEMORY_SCOPE_AGENT);
    union { u64 q[2]; bf16x8 v; } u;
    u.q[0] = lo; u.q[1] = hi;
    return u.v;
}

__device__ inline float fast_sigmoid(float x) {
    return __builtin_amdgcn_rcpf(1.f + __expf(-x));
}
__device__ inline float fast_tanh(float x) {
    float e = __expf(-2.f * fabsf(x));
    float t = (1.f - e) * __builtin_amdgcn_rcpf(1.f + e);
    return copysignf(t, x);
}

// ---------------------------------------------------------------------------
__global__ void cvt_f32_bf16(const float* __restrict__ src,
                             unsigned short* __restrict__ dst, int n)
{
    int i = (blockIdx.x * blockDim.x + threadIdx.x) * 4;
    if (i + 3 < n) {
        float4 v = *(const float4*)(src + i);
        ushort4 o;
        o.x = f2bf(v.x); o.y = f2bf(v.y); o.z = f2bf(v.z); o.w = f2bf(v.w);
        *(ushort4*)(dst + i) = o;
    }
}

// ---------------------------------------------------------------------------
// gx GEMM (layer 0 only): C[M][3072] = A[M][1024] @ Wbf[3072][1024]^T + bias
// ---------------------------------------------------------------------------
__global__ __launch_bounds__(256) void gemm_gx_bf16(
    const float* __restrict__ A, const unsigned short* __restrict__ Wbf,
    const float* __restrict__ bias, float* __restrict__ C, int M)
{
    __shared__ unsigned short As[128][72];
    __shared__ unsigned short Bs[128][72];
    const int tid = threadIdx.x;
    const int l  = tid & 63;
    const int w  = tid >> 6;
    const int wm = w >> 1, wn = w & 1;
    const int m0 = blockIdx.y * 128, n0 = blockIdx.x * 128;
    const int lr = l & 15, lk = (l >> 4) * 8;

    f32x4 acc[4][4] = {};

    const int arow = tid >> 4, acol = (tid & 15) * 4;
    const int brow = tid >> 3, bcol = (tid & 7) * 8;

    for (int k0 = 0; k0 < 1024; k0 += 64) {
        float4 av[8];
        #pragma unroll
        for (int r = 0; r < 8; ++r)
            av[r] = *(const float4*)(A + (size_t)(m0 + r * 16 + arow) * 1024 + k0 + acol);
        u16x8 bv[4];
        #pragma unroll
        for (int r = 0; r < 4; ++r)
            bv[r] = *(const u16x8*)(Wbf + (size_t)(n0 + r * 32 + brow) * 1024 + k0 + bcol);

        __syncthreads();
        #pragma unroll
        for (int r = 0; r < 8; ++r) {
            ushort4 o;
            o.x = f2bf(av[r].x); o.y = f2bf(av[r].y);
            o.z = f2bf(av[r].z); o.w = f2bf(av[r].w);
            *(ushort4*)&As[r * 16 + arow][acol] = o;
        }
        #pragma unroll
        for (int r = 0; r < 4; ++r)
            *(u16x8*)&Bs[r * 32 + brow][bcol] = bv[r];
        __syncthreads();

        #pragma unroll
        for (int kk = 0; kk < 2; ++kk) {
            bf16x8 af[4], bfr[4];
            #pragma unroll
            for (int i = 0; i < 4; ++i)
                af[i] = *(const bf16x8*)&As[wm * 64 + i * 16 + lr][kk * 32 + lk];
            #pragma unroll
            for (int j = 0; j < 4; ++j)
                bfr[j] = *(const bf16x8*)&Bs[wn * 64 + j * 16 + lr][kk * 32 + lk];
            #pragma unroll
            for (int i = 0; i < 4; ++i)
                #pragma unroll
                for (int j = 0; j < 4; ++j)
                    acc[i][j] = __builtin_amdgcn_mfma_f32_16x16x32_bf16(
                        af[i], bfr[j], acc[i][j], 0, 0, 0);
        }
    }

    #pragma unroll
    for (int j = 0; j < 4; ++j) {
        const int col = n0 + wn * 64 + j * 16 + lr;
        const float bv = bias[col];
        #pragma unroll
        for (int i = 0; i < 4; ++i) {
            const int rb = m0 + wm * 64 + i * 16 + (l >> 4) * 4;
            #pragma unroll
            for (int r = 0; r < 4; ++r)
                C[(size_t)(rb + r) * G3 + col] = acc[i][j][r] + bv;
        }
    }
}

// ---------------------------------------------------------------------------
// Layer-pipelined persistent recurrence: round r computes h0(c0+r) AND
// h1(c0+r-1) (1-round skew). 256 blocks x 256 thr, block = (jt, bg), 4 waves
// K-split. Round-5 protocol: agent h ping-pong, per-block flag after
// __syncthreads (vmcnt drain), wave-0 64-flag poll. Layer-1's input GEMM is
// folded in: acc1 = W_ih1 @ h0(t1) + W_hh1 @ h1(t1-1), reusing the h0 A-frags
// already loaded for layer 0. n-gate keeps split accumulators (r-multiplier).
// y0 never touches HBM. Rounds per chunk: tc+1 (513 total for one chunk).
// ---------------------------------------------------------------------------
__global__ __launch_bounds__(256, 1) void gru_pipe(
    const float* __restrict__ gx0,           // [tc][64][3072] chunk-local
    unsigned short* __restrict__ hbf0,       // 2 x [64][1024] bf16 ping-pong
    unsigned short* __restrict__ hbf1,
    const float* __restrict__ h0f_in,        // f32 h0 state before step c0
    const float* __restrict__ h1f_in,        // f32 h1 state before step c0
    float* __restrict__ h0f_out,             // f32 carry out (chunk end)
    float* __restrict__ h1f_out,
    const unsigned short* __restrict__ whh0, // [3072][1024] bf16
    const unsigned short* __restrict__ wih1,
    const unsigned short* __restrict__ whh1,
    const float* __restrict__ bhh0,          // [3072]
    const float* __restrict__ bih1,
    const float* __restrict__ bhh1,
    float* __restrict__ y1_all,              // [512][64][1024] (= d_out y)
    float* __restrict__ hn,                  // [2][64][1024]   (= d_out hn)
    unsigned int* __restrict__ flags,        // [4][64] stamp words
    int c0, int tc)
{
    __shared__ float red[4][64][29];   // 29: odd stride -> conflict-free

    const int tid = threadIdx.x;
    const int bid = blockIdx.x;
    const int jt = bid & 63;
    const int bg = bid >> 6;
    const int l   = tid & 63;
    const int ks  = tid >> 6;          // wave = k-slice (256 k)
    const int lr  = l & 15;
    const int lgrp = l >> 4;

    const unsigned short* hpb0 = hbf0 + (size_t)(bg * 16 + lr) * HID + ks * 256 + lgrp * 8;
    const unsigned short* hpb1 = hbf1 + (size_t)(bg * 16 + lr) * HID + ks * 256 + lgrp * 8;

    const size_t basew = ((size_t)(jt * 16 + lr) << 10) + ks * 256 + lgrp * 8;
    const size_t GS = (size_t)HID * HID;
    const unsigned short* w0 = whh0 + basew;
    const unsigned short* wi = wih1 + basew;
    const unsigned short* wh = whh1 + basew;

    // finalize coords: thread (fl, q) -> (col j, batch b)
    const int q  = tid >> 6;
    const int fl = tid & 63;
    const int j  = jt * 16 + (fl & 15);
    const int b  = bg * 16 + 4 * (fl >> 4) + q;
    const float b0r = bhh0[j], b0z = bhh0[HID + j], b0n = bhh0[2 * HID + j];
    const float b1r = bih1[j] + bhh1[j];               // r/z biases combine
    const float b1z = bih1[HID + j] + bhh1[HID + j];
    const float b1ni = bih1[2 * HID + j];              // n biases stay split
    const float b1nh = bhh1[2 * HID + j];

    float hreg0 = h0f_in[(size_t)b * HID + j];
    float hreg1 = h1f_in[(size_t)b * HID + j];

    float gxr = gx0[(size_t)b * G3 + j];
    float gxz = gx0[(size_t)b * G3 + HID + j];
    float gxn = gx0[(size_t)b * G3 + 2 * HID + j];

    for (int ts = 0; ts <= tc; ++ts) {
        const int t0 = c0 + ts;            // layer-0 step this round
        const int t1 = t0 - 1;             // layer-1 step this round
        const bool L0act = (ts < tc);
        const bool L1act = (ts > 0);
        const size_t coff0 = (size_t)(t0 & 1) * BH;        // h0(t0-1)
        const size_t noff0 = (size_t)((t0 + 1) & 1) * BH;  // h0(t0) out
        const size_t coff1 = (size_t)(t1 & 1) * BH;        // h1(t1-1)
        const size_t noff1 = (size_t)((t1 + 1) & 1) * BH;  // h1(t1) out
        const unsigned int stamp = (unsigned int)(c0 + ts + 1);

        // ---- A-operands: h0(t0-1) slice (used by BOTH layers), h1 inside loop
        bf16x8 a0v[8];
        #pragma unroll
        for (int kc = 0; kc < 8; ++kc)
            a0v[kc] = load_h8(hpb0 + coff0 + kc * 32);

        f32x4 ar0 = {0.f,0.f,0.f,0.f}, az0 = {0.f,0.f,0.f,0.f}, an0 = {0.f,0.f,0.f,0.f};
        f32x4 ar1 = {0.f,0.f,0.f,0.f}, az1 = {0.f,0.f,0.f,0.f};
        f32x4 ani = {0.f,0.f,0.f,0.f}, anh = {0.f,0.f,0.f,0.f};

        if (L0act) {
            #pragma unroll
            for (int kc = 0; kc < 8; ++kc) {
                ar0 = __builtin_amdgcn_mfma_f32_16x16x32_bf16(a0v[kc], *(const bf16x8*)(w0 + kc * 32),          ar0, 0, 0, 0);
                az0 = __builtin_amdgcn_mfma_f32_16x16x32_bf16(a0v[kc], *(const bf16x8*)(w0 + GS + kc * 32),     az0, 0, 0, 0);
                an0 = __builtin_amdgcn_mfma_f32_16x16x32_bf16(a0v[kc], *(const bf16x8*)(w0 + 2 * GS + kc * 32), an0, 0, 0, 0);
            }
        }
        if (L1act) {
            #pragma unroll
            for (int kc = 0; kc < 8; ++kc) {
                bf16x8 a1 = load_h8(hpb1 + coff1 + kc * 32);
                ar1 = __builtin_amdgcn_mfma_f32_16x16x32_bf16(a0v[kc], *(const bf16x8*)(wi + kc * 32),          ar1, 0, 0, 0);
                az1 = __builtin_amdgcn_mfma_f32_16x16x32_bf16(a0v[kc], *(const bf16x8*)(wi + GS + kc * 32),     az1, 0, 0, 0);
                ani = __builtin_amdgcn_mfma_f32_16x16x32_bf16(a0v[kc], *(const bf16x8*)(wi + 2 * GS + kc * 32), ani, 0, 0, 0);
                ar1 = __builtin_amdgcn_mfma_f32_16x16x32_bf16(a1,      *(const bf16x8*)(wh + kc * 32),          ar1, 0, 0, 0);
                az1 = __builtin_amdgcn_mfma_f32_16x16x32_bf16(a1,      *(const bf16x8*)(wh + GS + kc * 32),     az1, 0, 0, 0);
                anh = __builtin_amdgcn_mfma_f32_16x16x32_bf16(a1,      *(const bf16x8*)(wh + 2 * GS + kc * 32), anh, 0, 0, 0);
            }
        }

        if (L0act) {
            #pragma unroll
            for (int i = 0; i < 4; ++i) {
                red[ks][l][i]      = ar0[i];
                red[ks][l][4 + i]  = az0[i];
                red[ks][l][8 + i]  = an0[i];
            }
        }
        if (L1act) {
            #pragma unroll
            for (int i = 0; i < 4; ++i) {
                red[ks][l][12 + i] = ar1[i];
                red[ks][l][16 + i] = az1[i];
                red[ks][l][20 + i] = ani[i];
                red[ks][l][24 + i] = anh[i];
            }
        }
        __syncthreads();

        float sr0 = 0.f, sz0 = 0.f, sn0 = 0.f;
        float sr1 = 0.f, sz1 = 0.f, sni = 0.f, snh = 0.f;
        #pragma unroll
        for (int s = 0; s < 4; ++s) {
            sr0 += red[s][fl][q];       sz0 += red[s][fl][4 + q];  sn0 += red[s][fl][8 + q];
            sr1 += red[s][fl][12 + q];  sz1 += red[s][fl][16 + q];
            sni += red[s][fl][20 + q];  snh += red[s][fl][24 + q];
        }

        if (L0act) {
            const float rg = fast_sigmoid(gxr + sr0 + b0r);
            const float zg = fast_sigmoid(gxz + sz0 + b0z);
            const float ng = fast_tanh(gxn + rg * (sn0 + b0n));
            hreg0 = ng + zg * (hreg0 - ng);
            unsigned int myu = (unsigned int)f2bf(hreg0);
            unsigned int pu  = __shfl_xor(myu, 1);
            if (!(fl & 1))
                __hip_atomic_store((unsigned int*)(hbf0 + noff0 + (size_t)b * HID + j),
                                   myu | (pu << 16),
                                   __ATOMIC_RELAXED, __HIP_MEMORY_SCOPE_AGENT);
        }
        if (L1act) {
            const float rg = fast_sigmoid(sr1 + b1r);
            const float zg = fast_sigmoid(sz1 + b1z);
            const float ng = fast_tanh(sni + b1ni + rg * (snh + b1nh));
            hreg1 = ng + zg * (hreg1 - ng);
            unsigned int myu = (unsigned int)f2bf(hreg1);
            unsigned int pu  = __shfl_xor(myu, 1);
            if (!(fl & 1))
                __hip_atomic_store((unsigned int*)(hbf1 + noff1 + (size_t)b * HID + j),
                                   myu | (pu << 16),
                                   __ATOMIC_RELAXED, __HIP_MEMORY_SCOPE_AGENT);
        }

        __syncthreads();   // drains vmcnt(0): all h stores are at the LLC
        if (tid == 0)      // arrive: plain store, RMW-free
            __hip_atomic_store(&flags[bg * 64 + jt], stamp,
                               __ATOMIC_RELAXED, __HIP_MEMORY_SCOPE_AGENT);

        // off the arrive path (complete under the spin):
        if (L1act)
            y1_all[(size_t)t1 * BH + (size_t)b * HID + j] = hreg1;
        if (L0act && t0 == T_STEPS - 1)
            hn[(size_t)b * HID + j] = hreg0;
        if (L1act && t1 == T_STEPS - 1)
            hn[(size_t)BH + (size_t)b * HID + j] = hreg1;
        if (ts == tc - 1)
            h0f_out[(size_t)b * HID + j] = hreg0;
        if (ts == tc)
            h1f_out[(size_t)b * HID + j] = hreg1;

        const int tsn = (ts + 1 < tc) ? ts + 1 : (tc - 1);   // next gx0 round
        const float* gxp = gx0 + (size_t)tsn * BATCH * G3;
        const float ngxr = gxp[(size_t)b * G3 + j];
        const float ngxz = gxp[(size_t)b * G3 + HID + j];
        const float ngxn = gxp[(size_t)b * G3 + 2 * HID + j];

        if (tid < 64) {    // wave 0 polls all 64 producer flags of this bg
            for (;;) {
                unsigned int f = __hip_atomic_load(&flags[bg * 64 + tid],
                                                   __ATOMIC_RELAXED,
                                                   __HIP_MEMORY_SCOPE_AGENT);
                if (__ballot(f >= stamp) == ~0ull) break;
                __builtin_amdgcn_s_sleep(1);
            }
        }
        __syncthreads();   // all 64 bg-blocks' h visible; guards red reuse
        gxr = ngxr; gxz = ngxz; gxn = ngxn;
    }
}

// ---------------------------------------------------------------------------
extern "C" void kernel_launch(void* const* d_in, const int* in_sizes, int n_in,
                              void* d_out, int out_size, void* d_ws, size_t ws_size,
                              hipStream_t stream)
{
    const float* x    = (const float*)d_in[0];
    const float* h0   = (const float*)d_in[1];
    const float* wih0 = (const float*)d_in[2];
    const float* whh0 = (const float*)d_in[3];
    const float* bih0 = (const float*)d_in[4];
    const float* bhh0 = (const float*)d_in[5];
    const float* wih1 = (const float*)d_in[6];
    const float* whh1 = (const float*)d_in[7];
    const float* bih1 = (const float*)d_in[8];
    const float* bhh1 = (const float*)d_in[9];

    float* out = (float*)d_out;
    float* y   = out;                                  // [512][64][1024] = y1
    float* hn  = out + (size_t)T_STEPS * BH;           // [2][64][1024]

    const size_t WSZ = (size_t)G3 * HID;               // 3145728 elems
    unsigned short* wsu = (unsigned short*)d_ws;
    unsigned short* whh0_bf = wsu;
    unsigned short* wih0_bf = wsu + WSZ;
    unsigned short* wih1_bf = wsu + 2 * WSZ;
    unsigned short* whh1_bf = wsu + 3 * WSZ;
    unsigned short* hbf0 = wsu + 4 * WSZ;              // 2 x BH bf16
    unsigned short* hbf1 = hbf0 + 2 * (size_t)BH;      // 2 x BH bf16
    unsigned int* flags = (unsigned int*)(hbf1 + 2 * (size_t)BH);
    const size_t FLAG_N = 4 * 64;
    float* h0carry = (float*)((char*)flags + FLAG_N * sizeof(unsigned int));
    float* h1carry = h0carry + BH;
    float* gx = h1carry + BH;
    const size_t fixed_bytes = 4 * WSZ * 2 + 4 * (size_t)BH * 2
                             + FLAG_N * 4 + 2 * (size_t)BH * 4;
    const size_t gx_bytes = ws_size > fixed_bytes ? ws_size - fixed_bytes : 0;

    int TC = 512;
    while (TC > 2 && (size_t)TC * BATCH * G3 * 4 > gx_bytes) TC >>= 1;

    hipMemsetAsync(flags, 0, FLAG_N * sizeof(unsigned int), stream);

    cvt_f32_bf16<<<(int)(WSZ / 1024), 256, 0, stream>>>(whh0, whh0_bf, (int)WSZ);
    cvt_f32_bf16<<<(int)(WSZ / 1024), 256, 0, stream>>>(wih0, wih0_bf, (int)WSZ);
    cvt_f32_bf16<<<(int)(WSZ / 1024), 256, 0, stream>>>(wih1, wih1_bf, (int)WSZ);
    cvt_f32_bf16<<<(int)(WSZ / 1024), 256, 0, stream>>>(whh1, whh1_bf, (int)WSZ);

    // h inits: slot 0 of each ping-pong (round 0 reads slot t&1 = 0)
    cvt_f32_bf16<<<BH / 1024, 256, 0, stream>>>(h0, hbf0, BH);
    cvt_f32_bf16<<<BH / 1024, 256, 0, stream>>>(h0 + BH, hbf1, BH);

    for (int c0 = 0; c0 < T_STEPS; c0 += TC) {
        dim3 ggrid(G3 / 128, TC * BATCH / 128);
        gemm_gx_bf16<<<ggrid, 256, 0, stream>>>(
            x + (size_t)c0 * BH, wih0_bf, bih0, gx, TC * BATCH);

        const float* gxp = gx;
        const float* h0fi = (c0 == 0) ? h0 : h0carry;
        const float* h1fi = (c0 == 0) ? (h0 + BH) : h1carry;
        float* h0fo = h0carry;
        float* h1fo = h1carry;
        const unsigned short* w0p = whh0_bf;
        const unsigned short* wip = wih1_bf;
        const unsigned short* whp = whh1_bf;
        const float* b0p = bhh0;
        const float* bip = bih1;
        const float* bhp = bhh1;
        float* yp = y;
        float* hnp = hn;
        unsigned short* hb0 = hbf0;
        unsigned short* hb1 = hbf1;
        unsigned int* flp = flags;
        int c0v = c0, tcv = TC;
        void* kargs[] = {(void*)&gxp, (void*)&hb0, (void*)&hb1,
                         (void*)&h0fi, (void*)&h1fi, (void*)&h0fo, (void*)&h1fo,
                         (void*)&w0p, (void*)&wip, (void*)&whp,
                         (void*)&b0p, (void*)&bip, (void*)&bhp,
                         (void*)&yp, (void*)&hnp, (void*)&flp,
                         (void*)&c0v, (void*)&tcv};
        hipLaunchCooperativeKernel((const void*)gru_pipe,
                                   dim3(256), dim3(256), kargs, 0, stream);
    }
}

// Round 11
// 5754.454 us; speedup vs baseline: 1.3827x; 1.3827x over previous
//
#include <hip/hip_runtime.h>
#include <hip/hip_bf16.h>
#include <math.h>

#define T_STEPS 512
#define BATCH   64
#define HID     1024
#define G3      3072
#define BH      (BATCH * HID)

typedef __attribute__((ext_vector_type(8))) short          bf16x8;
typedef __attribute__((ext_vector_type(8))) unsigned short u16x8;
typedef __attribute__((ext_vector_type(4))) float          f32x4;
typedef unsigned long long u64;

__device__ inline unsigned short f2bf(float f) {
    __hip_bfloat16 h = __float2bfloat16(f);
    return *reinterpret_cast<unsigned short*>(&h);
}

// agent-scope (cross-XCD coherent) 16B load of bf16x8, bypassing stale L1/L2
__device__ inline bf16x8 load_h8(const unsigned short* p) {
    u64 lo = __hip_atomic_load((const u64*)p,       __ATOMIC_RELAXED, __HIP_MEMORY_SCOPE_AGENT);
    u64 hi = __hip_atomic_load((const u64*)(p + 4), __ATOMIC_RELAXED, __HIP_MEMORY_SCOPE_AGENT);
    union { u64 q[2]; bf16x8 v; } u;
    u.q[0] = lo; u.q[1] = hi;
    return u.v;
}

__device__ inline float fast_sigmoid(float x) {
    return __builtin_amdgcn_rcpf(1.f + __expf(-x));
}
__device__ inline float fast_tanh(float x) {
    float e = __expf(-2.f * fabsf(x));
    float t = (1.f - e) * __builtin_amdgcn_rcpf(1.f + e);
    return copysignf(t, x);
}

// ---------------------------------------------------------------------------
__global__ void cvt_f32_bf16(const float* __restrict__ src,
                             unsigned short* __restrict__ dst, int n)
{
    int i = (blockIdx.x * blockDim.x + threadIdx.x) * 4;
    if (i + 3 < n) {
        float4 v = *(const float4*)(src + i);
        ushort4 o;
        o.x = f2bf(v.x); o.y = f2bf(v.y); o.z = f2bf(v.z); o.w = f2bf(v.w);
        *(ushort4*)(dst + i) = o;
    }
}

// ---------------------------------------------------------------------------
// gx GEMM: C[M][3072] = A[M][1024](f32, cvt on the fly) @ Wbf[3072][1024]^T + b
// ---------------------------------------------------------------------------
__global__ __launch_bounds__(256) void gemm_gx_bf16(
    const float* __restrict__ A, const unsigned short* __restrict__ Wbf,
    const float* __restrict__ bias, float* __restrict__ C, int M)
{
    __shared__ unsigned short As[128][72];
    __shared__ unsigned short Bs[128][72];
    const int tid = threadIdx.x;
    const int l  = tid & 63;
    const int w  = tid >> 6;
    const int wm = w >> 1, wn = w & 1;
    const int m0 = blockIdx.y * 128, n0 = blockIdx.x * 128;
    const int lr = l & 15, lk = (l >> 4) * 8;

    f32x4 acc[4][4] = {};

    const int arow = tid >> 4, acol = (tid & 15) * 4;
    const int brow = tid >> 3, bcol = (tid & 7) * 8;

    for (int k0 = 0; k0 < 1024; k0 += 64) {
        float4 av[8];
        #pragma unroll
        for (int r = 0; r < 8; ++r)
            av[r] = *(const float4*)(A + (size_t)(m0 + r * 16 + arow) * 1024 + k0 + acol);
        u16x8 bv[4];
        #pragma unroll
        for (int r = 0; r < 4; ++r)
            bv[r] = *(const u16x8*)(Wbf + (size_t)(n0 + r * 32 + brow) * 1024 + k0 + bcol);

        __syncthreads();
        #pragma unroll
        for (int r = 0; r < 8; ++r) {
            ushort4 o;
            o.x = f2bf(av[r].x); o.y = f2bf(av[r].y);
            o.z = f2bf(av[r].z); o.w = f2bf(av[r].w);
            *(ushort4*)&As[r * 16 + arow][acol] = o;
        }
        #pragma unroll
        for (int r = 0; r < 4; ++r)
            *(u16x8*)&Bs[r * 32 + brow][bcol] = bv[r];
        __syncthreads();

        #pragma unroll
        for (int kk = 0; kk < 2; ++kk) {
            bf16x8 af[4], bfr[4];
            #pragma unroll
            for (int i = 0; i < 4; ++i)
                af[i] = *(const bf16x8*)&As[wm * 64 + i * 16 + lr][kk * 32 + lk];
            #pragma unroll
            for (int j = 0; j < 4; ++j)
                bfr[j] = *(const bf16x8*)&Bs[wn * 64 + j * 16 + lr][kk * 32 + lk];
            #pragma unroll
            for (int i = 0; i < 4; ++i)
                #pragma unroll
                for (int j = 0; j < 4; ++j)
                    acc[i][j] = __builtin_amdgcn_mfma_f32_16x16x32_bf16(
                        af[i], bfr[j], acc[i][j], 0, 0, 0);
        }
    }

    #pragma unroll
    for (int j = 0; j < 4; ++j) {
        const int col = n0 + wn * 64 + j * 16 + lr;
        const float bv = bias[col];
        #pragma unroll
        for (int i = 0; i < 4; ++i) {
            const int rb = m0 + wm * 64 + i * 16 + (l >> 4) * 4;
            #pragma unroll
            for (int r = 0; r < 4; ++r)
                C[(size_t)(rb + r) * G3 + col] = acc[i][j][r] + bv;
        }
    }
}

// ---------------------------------------------------------------------------
// Persistent recurrence (round-5 verified structure). RMW-free barrier:
// producer (jt,bg) stores a monotone stamp into its own flag word
// flags[bg*64+jt] (plain agent-scope store); consumer wave 0 polls all 64
// flags of its bg with one coalesced load + ballot. h-store->flag order
// guaranteed by the vmcnt(0) drain in the __syncthreads before the flag
// store. y-store, hn-store and gx-prefetch sit after the flag store (off the
// arrive path, hidden under the spin).
// ---------------------------------------------------------------------------
__global__ __launch_bounds__(256, 1) void gru_persist(
    const float* __restrict__ gx,            // [tc][64][3072] chunk-local
    unsigned short* __restrict__ hbf,        // 2 x [64][1024], parity = t&1
    const float* __restrict__ hprev0,        // [64][1024] f32 h before step t0
    const unsigned short* __restrict__ whh,  // [3072][1024] bf16
    const float* __restrict__ bhh,           // [3072]
    float* __restrict__ y_all,               // [512][64][1024]
    float* __restrict__ hn_dst,              // [64][1024] (this layer's hn)
    unsigned int* __restrict__ flags,        // [4][64] stamp words
    int step_base, int t0, int tc)
{
    __shared__ float red[4][64][13];

    const int tid = threadIdx.x;
    const int bid = blockIdx.x;
    const int jt = bid & 63;
    const int bg = bid >> 6;
    const int l   = tid & 63;
    const int ks  = tid >> 6;          // wave = k-slice (256 k)
    const int lr  = l & 15;
    const int lgrp = l >> 4;

    const unsigned short* hpb = hbf + (size_t)(bg * 16 + lr) * HID + ks * 256 + lgrp * 8;
    const unsigned short* wr  = whh + (size_t)(jt * 16 + lr) * HID + ks * 256 + lgrp * 8;
    const unsigned short* wz  = wr + (size_t)HID * HID;
    const unsigned short* wn  = wz + (size_t)HID * HID;

    // hoist this wave's W_hh slice into registers (loop-invariant)
    bf16x8 wvr[8], wvz[8], wvn[8];
    #pragma unroll
    for (int kc = 0; kc < 8; ++kc) {
        wvr[kc] = *(const bf16x8*)(wr + kc * 32);
        wvz[kc] = *(const bf16x8*)(wz + kc * 32);
        wvn[kc] = *(const bf16x8*)(wn + kc * 32);
    }

    // finalize coords: thread (fl, q) -> (col j, batch b)
    const int q  = tid >> 6;
    const int fl = tid & 63;
    const int j  = jt * 16 + (fl & 15);
    const int b  = bg * 16 + 4 * (fl >> 4) + q;
    const float brc = bhh[j], bzc = bhh[HID + j], bnc = bhh[2 * HID + j];
    float hreg = hprev0[(size_t)b * HID + j];

    float gxr = gx[(size_t)b * G3 + j];
    float gxz = gx[(size_t)b * G3 + HID + j];
    float gxn = gx[(size_t)b * G3 + 2 * HID + j];

    for (int ts = 0; ts < tc; ++ts) {
        const int t = t0 + ts;
        const size_t coff = (size_t)(t & 1) * BH;
        const size_t noff = (size_t)((t + 1) & 1) * BH;
        const unsigned int stamp = (unsigned int)(step_base + ts + 1);

        f32x4 ar = {0.f, 0.f, 0.f, 0.f};
        f32x4 az = {0.f, 0.f, 0.f, 0.f};
        f32x4 an = {0.f, 0.f, 0.f, 0.f};
        #pragma unroll
        for (int kc = 0; kc < 8; ++kc) {
            bf16x8 a = load_h8(hpb + coff + kc * 32);
            ar = __builtin_amdgcn_mfma_f32_16x16x32_bf16(a, wvr[kc], ar, 0, 0, 0);
            az = __builtin_amdgcn_mfma_f32_16x16x32_bf16(a, wvz[kc], az, 0, 0, 0);
            an = __builtin_amdgcn_mfma_f32_16x16x32_bf16(a, wvn[kc], an, 0, 0, 0);
        }
        #pragma unroll
        for (int i = 0; i < 4; ++i) {
            red[ks][l][i]     = ar[i];
            red[ks][l][4 + i] = az[i];
            red[ks][l][8 + i] = an[i];
        }
        __syncthreads();

        float sr = 0.f, sz = 0.f, sn = 0.f;
        #pragma unroll
        for (int s = 0; s < 4; ++s) {
            sr += red[s][fl][q];
            sz += red[s][fl][4 + q];
            sn += red[s][fl][8 + q];
        }
        const float rg = fast_sigmoid(gxr + sr + brc);
        const float zg = fast_sigmoid(gxz + sz + bzc);
        const float ng = fast_tanh(gxn + rg * (sn + bnc));
        hreg = ng + zg * (hreg - ng);

        // packed 4B agent-scope h store (lane pair shares one dword)
        unsigned int myu = (unsigned int)f2bf(hreg);
        unsigned int pu  = __shfl_xor(myu, 1);
        if (!(fl & 1))
            __hip_atomic_store((unsigned int*)(hbf + noff + (size_t)b * HID + j),
                               myu | (pu << 16),
                               __ATOMIC_RELAXED, __HIP_MEMORY_SCOPE_AGENT);

        __syncthreads();   // drains vmcnt(0): all h stores are at the LLC
        if (tid == 0)      // arrive: plain store, RMW-free
            __hip_atomic_store(&flags[bg * 64 + jt], stamp,
                               __ATOMIC_RELAXED, __HIP_MEMORY_SCOPE_AGENT);

        // off the arrive path: y store, hn store, next step's gx prefetch
        y_all[(size_t)t * BH + (size_t)b * HID + j] = hreg;
        if (t == T_STEPS - 1)
            hn_dst[(size_t)b * HID + j] = hreg;
        const int tsn = (ts + 1 < tc) ? ts + 1 : ts;
        const float* gxp = gx + (size_t)tsn * BATCH * G3;
        const float ngxr = gxp[(size_t)b * G3 + j];
        const float ngxz = gxp[(size_t)b * G3 + HID + j];
        const float ngxn = gxp[(size_t)b * G3 + 2 * HID + j];

        if (tid < 64) {    // wave 0 polls all 64 producer flags of this bg
            for (;;) {
                unsigned int f = __hip_atomic_load(&flags[bg * 64 + tid],
                                                   __ATOMIC_RELAXED,
                                                   __HIP_MEMORY_SCOPE_AGENT);
                if (__ballot(f >= stamp) == ~0ull) break;
                __builtin_amdgcn_s_sleep(1);
            }
        }
        __syncthreads();   // release: all 64 bg-blocks' h visible; guards red
        gxr = ngxr; gxz = ngxz; gxn = ngxn;
    }
}

// ---------------------------------------------------------------------------
extern "C" void kernel_launch(void* const* d_in, const int* in_sizes, int n_in,
                              void* d_out, int out_size, void* d_ws, size_t ws_size,
                              hipStream_t stream)
{
    const float* x    = (const float*)d_in[0];
    const float* h0   = (const float*)d_in[1];
    const float* wih[2] = {(const float*)d_in[2], (const float*)d_in[6]};
    const float* whh[2] = {(const float*)d_in[3], (const float*)d_in[7]};
    const float* bih[2] = {(const float*)d_in[4], (const float*)d_in[8]};
    const float* bhh[2] = {(const float*)d_in[5], (const float*)d_in[9]};

    float* out = (float*)d_out;
    float* y   = out;                                  // [512][64][1024]
    float* hn  = out + (size_t)T_STEPS * BH;           // [2][64][1024]

    const size_t WSZ = (size_t)G3 * HID;               // 3145728 elems
    unsigned short* wsu = (unsigned short*)d_ws;
    unsigned short* whh_bf[2] = {wsu, wsu + WSZ};
    unsigned short* wih_bf[2] = {wsu + 2 * WSZ, wsu + 3 * WSZ};
    unsigned short* hbf = wsu + 4 * WSZ;               // 2 x BH bf16 ping-pong
    unsigned int* flags = (unsigned int*)(wsu + 4 * WSZ + 2 * (size_t)BH);
    const size_t FLAG_N = 4 * 64;
    float* gx = (float*)((char*)flags + FLAG_N * sizeof(unsigned int));
    const size_t fixed_bytes = (4 * WSZ + 2 * (size_t)BH) * 2 + FLAG_N * 4;
    const size_t gx_bytes = ws_size > fixed_bytes ? ws_size - fixed_bytes : 0;

    int TC = 512;
    while (TC > 2 && (size_t)TC * BATCH * G3 * 4 > gx_bytes) TC >>= 1;

    hipMemsetAsync(flags, 0, FLAG_N * sizeof(unsigned int), stream);

    for (int layer = 0; layer < 2; ++layer) {
        cvt_f32_bf16<<<(int)(WSZ / 1024), 256, 0, stream>>>(whh[layer], whh_bf[layer], (int)WSZ);
        cvt_f32_bf16<<<(int)(WSZ / 1024), 256, 0, stream>>>(wih[layer], wih_bf[layer], (int)WSZ);
    }

    for (int layer = 0; layer < 2; ++layer) {
        const float* A_all = (layer == 0) ? x : y;
        const float* hinit = h0 + (size_t)layer * BH;

        cvt_f32_bf16<<<BH / 1024, 256, 0, stream>>>(hinit, hbf, BH);

        for (int c0 = 0; c0 < T_STEPS; c0 += TC) {
            dim3 ggrid(G3 / 128, TC * BATCH / 128);
            gemm_gx_bf16<<<ggrid, 256, 0, stream>>>(
                A_all + (size_t)c0 * BH, wih_bf[layer], bih[layer],
                gx, TC * BATCH);

            const float* gxp = gx;
            const float* hprev0 = (c0 == 0) ? hinit : (y + (size_t)(c0 - 1) * BH);
            const unsigned short* whhp = whh_bf[layer];
            const float* bhhp = bhh[layer];
            float* yp = y;
            float* hnp = hn + (size_t)layer * BH;
            unsigned short* hbfp = hbf;
            unsigned int* flp = flags;
            int sb = layer * T_STEPS + c0;
            int t0v = c0, tcv = TC;
            void* kargs[] = {(void*)&gxp, (void*)&hbfp, (void*)&hprev0,
                             (void*)&whhp, (void*)&bhhp, (void*)&yp,
                             (void*)&hnp, (void*)&flp,
                             (void*)&sb, (void*)&t0v, (void*)&tcv};
            hipLaunchCooperativeKernel((const void*)gru_persist,
                                       dim3(256), dim3(256), kargs, 0, stream);
        }
    }
}